// Round 1
// baseline (717.457 us; speedup 1.0000x reference)
//
#include <hip/hip_runtime.h>
#include <hip/hip_bf16.h>

namespace {

constexpr int Bn = 64, T1 = 128, T2 = 160, D = 768, M = 64;
constexpr int NTOT = T2 * M;     // 10240 (j-major, m-minor == output layout)
constexpr int BM = 128;          // i-tile (all of T1)
constexpr int BN = 128;          // jm-tile (2 j x 64 m)
constexpr int BK = 64;
constexpr int KSTEPS = D / BK;   // 12

typedef __bf16 bf16x8 __attribute__((ext_vector_type(8)));
typedef __bf16 bf16x4 __attribute__((ext_vector_type(4)));
typedef float  f32x4  __attribute__((ext_vector_type(4)));

__device__ __forceinline__ float fast_tanh(float x) {
  // tanh(x) = 1 - 2/(e^{2x}+1); exp overflow -> rcp(inf)=0 -> 1, underflow -> -1. OK.
  float e = __expf(2.0f * x);
  return 1.0f - 2.0f * __builtin_amdgcn_rcpf(e + 1.0f);
}

__global__ void cvt_v1_bf16(const float* __restrict__ x, __bf16* __restrict__ y, int n4) {
  int i = blockIdx.x * blockDim.x + threadIdx.x;
  if (i < n4) {
    f32x4 v = ((const f32x4*)x)[i];
    bf16x4 o;
    o[0] = (__bf16)v.x; o[1] = (__bf16)v.y; o[2] = (__bf16)v.z; o[3] = (__bf16)v.w;
    ((bf16x4*)y)[i] = o;
  }
}

template <bool PRE>
__launch_bounds__(256, 3)
__global__ void mpcos_kernel(const float* __restrict__ v1f,
                             const __bf16* __restrict__ v1b,
                             const float* __restrict__ v2,
                             const float* __restrict__ kern,
                             float* __restrict__ out) {
  __shared__ __bf16 Alds[BM * BK];  // 16 KB, row-major [i][k]
  __shared__ __bf16 Blds[BN * BK];  // 16 KB, row-major [jm][k]  (B^T form)

  const int t    = threadIdx.x;
  const int lane = t & 63;
  const int w    = t >> 6;          // wave 0..3
  const int bjm  = blockIdx.x;      // 0..79  (jm tile)
  const int bb   = blockIdx.y;      // 0..63  (batch)

  // ---- staging thread mapping: row = t>>1 (0..127), k-half = (t&1)*32 ----
  const int srow = t >> 1;
  const int skh  = (t & 1) * 32;
  const int sm   = srow & (M - 1);  // kernel row
  const int sj   = srow >> 6;       // local j (0/1)
  const float* kp  = kern + sm * D + skh;
  const float* v2p = v2 + ((size_t)(bb * T2 + bjm * 2 + sj)) * D + skh;
  const float* v1p = v1f + ((size_t)bb * T1 + srow) * D + skh;  // fallback path

  // ---- async A mapping (PRE path): lane covers row w*32+q*8+(lane>>3), col (lane&7)*8
  const __bf16* av1 =
      v1b + (size_t)bb * T1 * D + (size_t)(w * 32 + (lane >> 3)) * D + (lane & 7) * 8;

  // ---- wave compute tile: 64x64 at (wrow, wcol) ----
  const int wrow = (w & 1) * 64;
  const int wcol = (w >> 1) * 64;
  const int lr = lane & 15;   // MFMA n/m index
  const int lg = lane >> 4;   // MFMA k-group

  f32x4 acc[4][4] = {};

  for (int ks = 0; ks < KSTEPS; ++ks) {
    const int kb = ks * BK;
    __syncthreads();  // previous tile's ds_reads done

    if (PRE) {
      // A-tile: bf16 v1 straight to LDS, 4x global_load_lds_dwordx4 per wave
#pragma unroll
      for (int q = 0; q < 4; ++q) {
        __builtin_amdgcn_global_load_lds(
            (const __attribute__((address_space(1))) void*)(av1 + kb + q * 8 * D),
            (__attribute__((address_space(3))) void*)&Alds[(w * 32 + q * 8) * BK],
            16, 0, 0);
      }
    } else {
      const f32x4* a4 = (const f32x4*)(v1p + kb);
#pragma unroll
      for (int q = 0; q < 4; ++q) {
        f32x4 x0 = a4[2 * q], x1 = a4[2 * q + 1];
        bf16x8 wv;
        wv[0] = (__bf16)x0.x; wv[1] = (__bf16)x0.y; wv[2] = (__bf16)x0.z; wv[3] = (__bf16)x0.w;
        wv[4] = (__bf16)x1.x; wv[5] = (__bf16)x1.y; wv[6] = (__bf16)x1.z; wv[7] = (__bf16)x1.w;
        *(bf16x8*)&Blds[0] = wv;  // placeholder avoided below
        *(bf16x8*)&Alds[srow * BK + skh + q * 8] = wv;
      }
    }

    // B'-tile: kernel[m,k] * v2[j,k] in fp32, convert, b128 LDS writes
    const f32x4* k4 = (const f32x4*)(kp + kb);
    const f32x4* u4 = (const f32x4*)(v2p + kb);
#pragma unroll
    for (int q = 0; q < 4; ++q) {
      f32x4 a0 = k4[2 * q], a1 = k4[2 * q + 1];
      f32x4 b0 = u4[2 * q], b1 = u4[2 * q + 1];
      bf16x8 wv;
      wv[0] = (__bf16)(a0.x * b0.x);
      wv[1] = (__bf16)(a0.y * b0.y);
      wv[2] = (__bf16)(a0.z * b0.z);
      wv[3] = (__bf16)(a0.w * b0.w);
      wv[4] = (__bf16)(a1.x * b1.x);
      wv[5] = (__bf16)(a1.y * b1.y);
      wv[6] = (__bf16)(a1.z * b1.z);
      wv[7] = (__bf16)(a1.w * b1.w);
      *(bf16x8*)&Blds[srow * BK + skh + q * 8] = wv;
    }

    __syncthreads();  // staging (incl. global_load_lds vmcnt) drained

#pragma unroll
    for (int kk = 0; kk < BK; kk += 32) {
      bf16x8 af[4], bfr[4];
#pragma unroll
      for (int ii = 0; ii < 4; ++ii)
        af[ii] = *(const bf16x8*)&Alds[(wrow + ii * 16 + lr) * BK + kk + lg * 8];
#pragma unroll
      for (int jj = 0; jj < 4; ++jj)
        bfr[jj] = *(const bf16x8*)&Blds[(wcol + jj * 16 + lr) * BK + kk + lg * 8];
#pragma unroll
      for (int ii = 0; ii < 4; ++ii)
#pragma unroll
        for (int jj = 0; jj < 4; ++jj)
          acc[ii][jj] = __builtin_amdgcn_mfma_f32_16x16x32_bf16(
              af[ii], bfr[jj], acc[ii][jj], 0, 0, 0);
    }
  }

  // ---- epilogue: tanh + store. C/D: col = lane&15, row = (lane>>4)*4 + reg ----
  float* obase = out + (size_t)bb * T1 * NTOT + (size_t)bjm * BN;
#pragma unroll
  for (int ii = 0; ii < 4; ++ii) {
#pragma unroll
    for (int r = 0; r < 4; ++r) {
      const int row = wrow + ii * 16 + lg * 4 + r;
      float* orow = obase + (size_t)row * NTOT + wcol + lr;
#pragma unroll
      for (int jj = 0; jj < 4; ++jj)
        orow[jj * 16] = fast_tanh(acc[ii][jj][r]);
    }
  }
}

}  // namespace

extern "C" void kernel_launch(void* const* d_in, const int* in_sizes, int n_in,
                              void* d_out, int out_size, void* d_ws, size_t ws_size,
                              hipStream_t stream) {
  const float* v1   = (const float*)d_in[0];
  const float* v2   = (const float*)d_in[1];
  const float* kern = (const float*)d_in[2];
  float* out = (float*)d_out;

  const size_t need = (size_t)Bn * T1 * D * sizeof(__bf16);  // 12.6 MB
  if (ws_size >= need) {
    __bf16* v1b = (__bf16*)d_ws;
    const int n4 = Bn * T1 * D / 4;  // 1572864
    cvt_v1_bf16<<<n4 / 256, 256, 0, stream>>>(v1, v1b, n4);
    mpcos_kernel<true><<<dim3(NTOT / BN, Bn), 256, 0, stream>>>(v1, v1b, v2, kern, out);
  } else {
    mpcos_kernel<false><<<dim3(NTOT / BN, Bn), 256, 0, stream>>>(v1, nullptr, v2, kern, out);
  }
}

// Round 2
// 709.993 us; speedup vs baseline: 1.0105x; 1.0105x over previous
//
#include <hip/hip_runtime.h>
#include <hip/hip_bf16.h>

namespace {

constexpr int Bn = 64, T1 = 128, T2 = 160, D = 768, M = 64;
constexpr int NTOT = T2 * M;     // 10240 (j-major, m-minor == output layout)
constexpr int BM = 128;          // i-tile (all of T1)
constexpr int BN = 128;          // jm-tile (2 j x 64 m)
constexpr int BK = 64;
constexpr int KSTEPS = D / BK;   // 12

typedef __bf16 bf16x8 __attribute__((ext_vector_type(8)));
typedef __bf16 bf16x4 __attribute__((ext_vector_type(4)));
typedef float  f32x4  __attribute__((ext_vector_type(4)));

__device__ __forceinline__ float fast_tanh(float x) {
  // tanh(x) = 1 - 2/(e^{2x}+1); exp overflow -> rcp(inf)=0 -> 1, underflow -> -1. OK.
  float e = __expf(2.0f * x);
  return 1.0f - 2.0f * __builtin_amdgcn_rcpf(e + 1.0f);
}

__global__ void cvt_v1_bf16(const float* __restrict__ x, __bf16* __restrict__ y, int n4) {
  int i = blockIdx.x * blockDim.x + threadIdx.x;
  if (i < n4) {
    f32x4 v = ((const f32x4*)x)[i];
    bf16x4 o;
    o[0] = (__bf16)v.x; o[1] = (__bf16)v.y; o[2] = (__bf16)v.z; o[3] = (__bf16)v.w;
    ((bf16x4*)y)[i] = o;
  }
}

// LDS layout (both tiles): row-major 128 rows x 64 bf16 (128 B = 8 chunks of
// 16 B), with the 16B-chunk index XOR-swizzled by (row & 7):
//   stored_chunk = logical_chunk ^ (row & 7)
// -> a fragment read (16 lanes, same k-chunk, rows differing in low 3 bits)
//    spreads over all 8 bank groups; every 4-bank group gets exactly 8 of a
//    wave's 64 chunks = minimal distribution = conflict-free.
// global_load_lds writes lane-contiguously, so the swizzle is implemented on
// the A path by permuting each lane's GLOBAL source chunk instead.

template <bool PRE>
__launch_bounds__(256, 3)
__global__ void mpcos_kernel(const float* __restrict__ v1f,
                             const __bf16* __restrict__ v1b,
                             const float* __restrict__ v2,
                             const float* __restrict__ kern,
                             float* __restrict__ out) {
  __shared__ __bf16 Alds[BM * BK];  // 16 KB
  __shared__ __bf16 Blds[BN * BK];  // 16 KB

  const int t    = threadIdx.x;
  const int lane = t & 63;
  const int w    = t >> 6;          // wave 0..3
  const int bjm  = blockIdx.x;      // 0..79  (jm tile)
  const int bb   = blockIdx.y;      // 0..63  (batch)

  // ---- staging thread mapping: row = t>>1 (0..127), k-half = (t&1)*32 ----
  const int srow = t >> 1;
  const int sc4  = (t & 1) * 4;     // logical chunk base (0 or 4)
  const int sm   = srow & (M - 1);  // kernel row
  const int sj   = srow >> 6;       // local j (0/1)
  const int ssw  = srow & 7;        // swizzle key for this staging row
  const float* kp  = kern + sm * D + sc4 * 8;
  const float* v2p = v2 + ((size_t)(bb * T2 + bjm * 2 + sj)) * D + sc4 * 8;
  const float* v1p = v1f + ((size_t)bb * T1 + srow) * D + sc4 * 8;  // fallback

  // ---- async A mapping (PRE): lane L covers row base+(L>>3); its contiguous
  // LDS slot is stored-chunk (L&7), i.e. logical chunk (L&7)^(row&7) = (L&7)^(L>>3).
  const __bf16* av1 = v1b + (size_t)bb * T1 * D
                    + (size_t)(w * 32 + (lane >> 3)) * D
                    + ((lane & 7) ^ (lane >> 3)) * 8;

  // ---- wave compute tile: 64x64 at (wrow, wcol) ----
  const int wrow = (w & 1) * 64;
  const int wcol = (w >> 1) * 64;
  const int lr  = lane & 15;   // MFMA n/m index
  const int lg  = lane >> 4;   // MFMA k-group
  const int lr7 = lr & 7;      // row&7 of every fragment row this lane touches

  f32x4 acc[4][4] = {};

  for (int ks = 0; ks < KSTEPS; ++ks) {
    const int kb = ks * BK;
    __syncthreads();  // previous tile's ds_reads done

    if (PRE) {
#pragma unroll
      for (int q = 0; q < 4; ++q) {
        __builtin_amdgcn_global_load_lds(
            (const __attribute__((address_space(1))) void*)(av1 + kb + q * 8 * D),
            (__attribute__((address_space(3))) void*)&Alds[(w * 32 + q * 8) * BK],
            16, 0, 0);
      }
    } else {
      const f32x4* a4 = (const f32x4*)(v1p + kb);
#pragma unroll
      for (int q = 0; q < 4; ++q) {
        f32x4 x0 = a4[2 * q], x1 = a4[2 * q + 1];
        bf16x8 wv;
        wv[0] = (__bf16)x0.x; wv[1] = (__bf16)x0.y; wv[2] = (__bf16)x0.z; wv[3] = (__bf16)x0.w;
        wv[4] = (__bf16)x1.x; wv[5] = (__bf16)x1.y; wv[6] = (__bf16)x1.z; wv[7] = (__bf16)x1.w;
        *(bf16x8*)&Alds[srow * BK + (((sc4 + q) ^ ssw) * 8)] = wv;
      }
    }

    // B'-tile: kernel[m,k] * v2[j,k] in fp32, convert, swizzled b128 LDS writes
    const f32x4* k4 = (const f32x4*)(kp + kb);
    const f32x4* u4 = (const f32x4*)(v2p + kb);
#pragma unroll
    for (int q = 0; q < 4; ++q) {
      f32x4 a0 = k4[2 * q], a1 = k4[2 * q + 1];
      f32x4 b0 = u4[2 * q], b1 = u4[2 * q + 1];
      bf16x8 wv;
      wv[0] = (__bf16)(a0.x * b0.x);
      wv[1] = (__bf16)(a0.y * b0.y);
      wv[2] = (__bf16)(a0.z * b0.z);
      wv[3] = (__bf16)(a0.w * b0.w);
      wv[4] = (__bf16)(a1.x * b1.x);
      wv[5] = (__bf16)(a1.y * b1.y);
      wv[6] = (__bf16)(a1.z * b1.z);
      wv[7] = (__bf16)(a1.w * b1.w);
      *(bf16x8*)&Blds[srow * BK + (((sc4 + q) ^ ssw) * 8)] = wv;
    }

    __syncthreads();  // staging (incl. global_load_lds vmcnt) drained

#pragma unroll
    for (int kk = 0; kk < BK; kk += 32) {
      const int cb = kk >> 3;  // logical chunk base: 0 or 4
      const int st = (((cb + lg) ^ lr7) * 8);
      bf16x8 af[4], bfr[4];
#pragma unroll
      for (int ii = 0; ii < 4; ++ii)
        af[ii] = *(const bf16x8*)&Alds[(wrow + ii * 16 + lr) * BK + st];
#pragma unroll
      for (int jj = 0; jj < 4; ++jj)
        bfr[jj] = *(const bf16x8*)&Blds[(wcol + jj * 16 + lr) * BK + st];
#pragma unroll
      for (int ii = 0; ii < 4; ++ii)
#pragma unroll
        for (int jj = 0; jj < 4; ++jj)
          acc[ii][jj] = __builtin_amdgcn_mfma_f32_16x16x32_bf16(
              af[ii], bfr[jj], acc[ii][jj], 0, 0, 0);
    }
  }

  // ---- epilogue: tanh + store. C/D: col = lane&15, row = (lane>>4)*4 + reg ----
  float* obase = out + (size_t)bb * T1 * NTOT + (size_t)bjm * BN;
#pragma unroll
  for (int ii = 0; ii < 4; ++ii) {
#pragma unroll
    for (int r = 0; r < 4; ++r) {
      const int row = wrow + ii * 16 + lg * 4 + r;
      float* orow = obase + (size_t)row * NTOT + wcol + lr;
#pragma unroll
      for (int jj = 0; jj < 4; ++jj)
        orow[jj * 16] = fast_tanh(acc[ii][jj][r]);
    }
  }
}

}  // namespace

extern "C" void kernel_launch(void* const* d_in, const int* in_sizes, int n_in,
                              void* d_out, int out_size, void* d_ws, size_t ws_size,
                              hipStream_t stream) {
  const float* v1   = (const float*)d_in[0];
  const float* v2   = (const float*)d_in[1];
  const float* kern = (const float*)d_in[2];
  float* out = (float*)d_out;

  const size_t need = (size_t)Bn * T1 * D * sizeof(__bf16);  // 12.6 MB
  if (ws_size >= need) {
    __bf16* v1b = (__bf16*)d_ws;
    const int n4 = Bn * T1 * D / 4;  // 1572864
    cvt_v1_bf16<<<n4 / 256, 256, 0, stream>>>(v1, v1b, n4);
    mpcos_kernel<true><<<dim3(NTOT / BN, Bn), 256, 0, stream>>>(v1, v1b, v2, kern, out);
  } else {
    mpcos_kernel<false><<<dim3(NTOT / BN, Bn), 256, 0, stream>>>(v1, nullptr, v2, kern, out);
  }
}

// Round 3
// 495.348 us; speedup vs baseline: 1.4484x; 1.4333x over previous
//
#include <hip/hip_runtime.h>
#include <hip/hip_bf16.h>

namespace {

constexpr int Bn = 64, T1 = 128, T2 = 160, D = 768, M = 64;
constexpr int NTOT = T2 * M;     // 10240 (j-major, m-minor == output layout)
constexpr int BM = 128;          // i-tile (all of T1)
constexpr int BN = 128;          // jm-tile (2 j x 64 m)
constexpr int BK = 32;
constexpr int KSTEPS = D / BK;   // 24

typedef __bf16 bf16x8 __attribute__((ext_vector_type(8)));
typedef __bf16 bf16x4 __attribute__((ext_vector_type(4)));
typedef float  f32x4  __attribute__((ext_vector_type(4)));

__device__ __forceinline__ float fast_tanh(float x) {
  // tanh(x) = 1 - 2/(e^{2x}+1); exp overflow -> rcp(inf)=0 -> 1, underflow -> -1.
  float e = __expf(2.0f * x);
  return 1.0f - 2.0f * __builtin_amdgcn_rcpf(e + 1.0f);
}

__global__ void cvt_bf16(const float* __restrict__ x, __bf16* __restrict__ y, int n4) {
  int i = blockIdx.x * blockDim.x + threadIdx.x;
  if (i < n4) {
    f32x4 v = ((const f32x4*)x)[i];
    bf16x4 o;
    o[0] = (__bf16)v.x; o[1] = (__bf16)v.y; o[2] = (__bf16)v.z; o[3] = (__bf16)v.w;
    ((bf16x4*)y)[i] = o;
  }
}

// product of two bf16x8 (as raw uint4 bit patterns) in fp32, repacked to bf16x8
__device__ __forceinline__ bf16x8 mul_bb(uint4 a, uint4 b) {
  const unsigned hm = 0xffff0000u;
  bf16x8 r;
  float al, ah, bl, bh;
  al = __uint_as_float(a.x << 16); ah = __uint_as_float(a.x & hm);
  bl = __uint_as_float(b.x << 16); bh = __uint_as_float(b.x & hm);
  r[0] = (__bf16)(al * bl); r[1] = (__bf16)(ah * bh);
  al = __uint_as_float(a.y << 16); ah = __uint_as_float(a.y & hm);
  bl = __uint_as_float(b.y << 16); bh = __uint_as_float(b.y & hm);
  r[2] = (__bf16)(al * bl); r[3] = (__bf16)(ah * bh);
  al = __uint_as_float(a.z << 16); ah = __uint_as_float(a.z & hm);
  bl = __uint_as_float(b.z << 16); bh = __uint_as_float(b.z & hm);
  r[4] = (__bf16)(al * bl); r[5] = (__bf16)(ah * bh);
  al = __uint_as_float(a.w << 16); ah = __uint_as_float(a.w & hm);
  bl = __uint_as_float(b.w << 16); bh = __uint_as_float(b.w & hm);
  r[6] = (__bf16)(al * bl); r[7] = (__bf16)(ah * bh);
  return r;
}

// ---------------- fast path: bf16 inputs, LDS double-buffer, 1 barrier/step ----
__launch_bounds__(256, 4)
__global__ void mpcos_fast(const __bf16* __restrict__ v1b,
                           const __bf16* __restrict__ v2b,
                           const __bf16* __restrict__ kb,
                           float* __restrict__ out) {
  __shared__ __bf16 Al[2][BM * BK];  // 2 x 8 KB
  __shared__ __bf16 Bl[2][BN * BK];  // 2 x 8 KB

  const int t    = threadIdx.x;
  const int lane = t & 63;
  const int w    = t >> 6;
  const int bjm  = blockIdx.x;   // 0..79
  const int bb   = blockIdx.y;   // 0..63

  // ---- B staging mapping: thread -> (m = t>>2, 16B chunk c = t&3); kern slice
  // shared by both j-passes. Wave writes are contiguous 1 KB -> conflict-free.
  const int sm = t >> 2, sc = t & 3;
  const __bf16* kp   = kb + sm * D + sc * 8;
  const __bf16* v2p0 = v2b + ((size_t)(bb * T2 + bjm * 2)) * D + sc * 8;
  const __bf16* v2p1 = v2p0 + D;
  const int boff = sm * BK + sc * 8;

  // ---- A staging via global_load_lds: instr q covers 16 rows (1 KB contiguous)
  const int arow = w * 32 + (lane >> 2);
  const __bf16* av1 = v1b + ((size_t)bb * T1 + arow) * D + (lane & 3) * 8;
  const int adst = (w * 32) * BK;

  // ---- wave compute tile 64x64 ----
  const int wrow = (w & 1) * 64;
  const int wcol = (w >> 1) * 64;
  const int lr = lane & 15, lg = lane >> 4;

  f32x4 acc[4][4] = {};

  // ---- prologue: stage step 0 into buffer 0 ----
  {
#pragma unroll
    for (int q = 0; q < 2; ++q)
      __builtin_amdgcn_global_load_lds(
          (const __attribute__((address_space(1))) void*)(av1 + q * 16 * D),
          (__attribute__((address_space(3))) void*)&Al[0][adst + q * 16 * BK],
          16, 0, 0);
    uint4 k0 = *(const uint4*)kp;
    uint4 u0 = *(const uint4*)v2p0;
    uint4 u1 = *(const uint4*)v2p1;
    *(bf16x8*)&Bl[0][boff]            = mul_bb(k0, u0);
    *(bf16x8*)&Bl[0][64 * BK + boff]  = mul_bb(k0, u1);
    __syncthreads();
  }

  int cur = 0;
  for (int ks = 0; ks < KSTEPS; ++ks) {
    const int nxt = cur ^ 1;
    const bool more = (ks + 1 < KSTEPS);
    uint4 pk, pu0, pu1;
    if (more) {
      const int ko = (ks + 1) * BK;
      // async A -> other buffer; in flight across compute, drained at barrier
#pragma unroll
      for (int q = 0; q < 2; ++q)
        __builtin_amdgcn_global_load_lds(
            (const __attribute__((address_space(1))) void*)(av1 + ko + q * 16 * D),
            (__attribute__((address_space(3))) void*)&Al[nxt][adst + q * 16 * BK],
            16, 0, 0);
      // B register prefetch; consumed after compute
      pk  = *(const uint4*)(kp + ko);
      pu0 = *(const uint4*)(v2p0 + ko);
      pu1 = *(const uint4*)(v2p1 + ko);
    }

    // ---- compute step ks from buffer cur ----
    bf16x8 af[4], bfr[4];
#pragma unroll
    for (int ii = 0; ii < 4; ++ii)
      af[ii] = *(const bf16x8*)&Al[cur][(wrow + ii * 16 + lr) * BK + lg * 8];
#pragma unroll
    for (int jj = 0; jj < 4; ++jj)
      bfr[jj] = *(const bf16x8*)&Bl[cur][(wcol + jj * 16 + lr) * BK + lg * 8];
#pragma unroll
    for (int ii = 0; ii < 4; ++ii)
#pragma unroll
      for (int jj = 0; jj < 4; ++jj)
        acc[ii][jj] = __builtin_amdgcn_mfma_f32_16x16x32_bf16(
            af[ii], bfr[jj], acc[ii][jj], 0, 0, 0);

    if (more) {
      *(bf16x8*)&Bl[nxt][boff]           = mul_bb(pk, pu0);
      *(bf16x8*)&Bl[nxt][64 * BK + boff] = mul_bb(pk, pu1);
      __syncthreads();
    }
    cur = nxt;
  }

  // ---- epilogue: tanh + store. C/D: col = lane&15, row = (lane>>4)*4 + reg ----
  float* obase = out + (size_t)bb * T1 * NTOT + (size_t)bjm * BN;
#pragma unroll
  for (int ii = 0; ii < 4; ++ii) {
#pragma unroll
    for (int r = 0; r < 4; ++r) {
      const int row = wrow + ii * 16 + lg * 4 + r;
      float* orow = obase + (size_t)row * NTOT + wcol + lr;
#pragma unroll
      for (int jj = 0; jj < 4; ++jj)
        orow[jj * 16] = fast_tanh(acc[ii][jj][r]);
    }
  }
}

// ---------------- fallback (ws too small): proven round-2 single-buffer fp32 ----
__launch_bounds__(256, 3)
__global__ void mpcos_ref(const float* __restrict__ v1f,
                          const float* __restrict__ v2,
                          const float* __restrict__ kern,
                          float* __restrict__ out) {
  constexpr int BKr = 64;
  __shared__ __bf16 Alds[BM * BKr];
  __shared__ __bf16 Blds[BN * BKr];

  const int t = threadIdx.x, lane = t & 63, w = t >> 6;
  const int bjm = blockIdx.x, bb = blockIdx.y;
  const int srow = t >> 1, sc4 = (t & 1) * 4;
  const int sm = srow & (M - 1), sj = srow >> 6, ssw = srow & 7;
  const float* kp  = kern + sm * D + sc4 * 8;
  const float* v2p = v2 + ((size_t)(bb * T2 + bjm * 2 + sj)) * D + sc4 * 8;
  const float* v1p = v1f + ((size_t)bb * T1 + srow) * D + sc4 * 8;
  const int wrow = (w & 1) * 64, wcol = (w >> 1) * 64;
  const int lr = lane & 15, lg = lane >> 4, lr7 = lr & 7;

  f32x4 acc[4][4] = {};
  for (int ks = 0; ks < D / BKr; ++ks) {
    const int kb = ks * BKr;
    __syncthreads();
    const f32x4* a4 = (const f32x4*)(v1p + kb);
#pragma unroll
    for (int q = 0; q < 4; ++q) {
      f32x4 x0 = a4[2 * q], x1 = a4[2 * q + 1];
      bf16x8 wv;
      wv[0] = (__bf16)x0.x; wv[1] = (__bf16)x0.y; wv[2] = (__bf16)x0.z; wv[3] = (__bf16)x0.w;
      wv[4] = (__bf16)x1.x; wv[5] = (__bf16)x1.y; wv[6] = (__bf16)x1.z; wv[7] = (__bf16)x1.w;
      *(bf16x8*)&Alds[srow * BKr + (((sc4 + q) ^ ssw) * 8)] = wv;
    }
    const f32x4* k4 = (const f32x4*)(kp + kb);
    const f32x4* u4 = (const f32x4*)(v2p + kb);
#pragma unroll
    for (int q = 0; q < 4; ++q) {
      f32x4 a0 = k4[2 * q], a1 = k4[2 * q + 1];
      f32x4 b0 = u4[2 * q], b1 = u4[2 * q + 1];
      bf16x8 wv;
      wv[0] = (__bf16)(a0.x * b0.x); wv[1] = (__bf16)(a0.y * b0.y);
      wv[2] = (__bf16)(a0.z * b0.z); wv[3] = (__bf16)(a0.w * b0.w);
      wv[4] = (__bf16)(a1.x * b1.x); wv[5] = (__bf16)(a1.y * b1.y);
      wv[6] = (__bf16)(a1.z * b1.z); wv[7] = (__bf16)(a1.w * b1.w);
      *(bf16x8*)&Blds[srow * BKr + (((sc4 + q) ^ ssw) * 8)] = wv;
    }
    __syncthreads();
#pragma unroll
    for (int kk = 0; kk < BKr; kk += 32) {
      const int cb = kk >> 3;
      const int st = (((cb + lg) ^ lr7) * 8);
      bf16x8 af[4], bfr[4];
#pragma unroll
      for (int ii = 0; ii < 4; ++ii)
        af[ii] = *(const bf16x8*)&Alds[(wrow + ii * 16 + lr) * BKr + st];
#pragma unroll
      for (int jj = 0; jj < 4; ++jj)
        bfr[jj] = *(const bf16x8*)&Blds[(wcol + jj * 16 + lr) * BKr + st];
#pragma unroll
      for (int ii = 0; ii < 4; ++ii)
#pragma unroll
        for (int jj = 0; jj < 4; ++jj)
          acc[ii][jj] = __builtin_amdgcn_mfma_f32_16x16x32_bf16(
              af[ii], bfr[jj], acc[ii][jj], 0, 0, 0);
    }
  }
  float* obase = out + (size_t)bb * T1 * NTOT + (size_t)bjm * BN;
#pragma unroll
  for (int ii = 0; ii < 4; ++ii)
#pragma unroll
    for (int r = 0; r < 4; ++r) {
      const int row = wrow + ii * 16 + lg * 4 + r;
      float* orow = obase + (size_t)row * NTOT + wcol + lr;
#pragma unroll
      for (int jj = 0; jj < 4; ++jj)
        orow[jj * 16] = fast_tanh(acc[ii][jj][r]);
    }
}

}  // namespace

extern "C" void kernel_launch(void* const* d_in, const int* in_sizes, int n_in,
                              void* d_out, int out_size, void* d_ws, size_t ws_size,
                              hipStream_t stream) {
  const float* v1   = (const float*)d_in[0];
  const float* v2   = (const float*)d_in[1];
  const float* kern = (const float*)d_in[2];
  float* out = (float*)d_out;

  const size_t n_v1 = (size_t)Bn * T1 * D;   // 6,291,456
  const size_t n_v2 = (size_t)Bn * T2 * D;   // 7,864,320
  const size_t n_k  = (size_t)M * D;         // 49,152
  const size_t off_v2 = n_v1 * 2;            // bytes
  const size_t off_k  = off_v2 + n_v2 * 2;
  const size_t need   = off_k + n_k * 2;     // ~28.4 MB

  if (ws_size >= need) {
    __bf16* v1b = (__bf16*)((char*)d_ws);
    __bf16* v2b = (__bf16*)((char*)d_ws + off_v2);
    __bf16* kb  = (__bf16*)((char*)d_ws + off_k);
    cvt_bf16<<<(int)(n_v1 / 4 / 256), 256, 0, stream>>>(v1, v1b, (int)(n_v1 / 4));
    cvt_bf16<<<(int)(n_v2 / 4 / 256), 256, 0, stream>>>(v2, v2b, (int)(n_v2 / 4));
    cvt_bf16<<<(int)(n_k  / 4 / 256), 256, 0, stream>>>(kern, kb, (int)(n_k / 4));
    mpcos_fast<<<dim3(NTOT / BN, Bn), 256, 0, stream>>>(v1b, v2b, kb, out);
  } else {
    mpcos_ref<<<dim3(NTOT / BN, Bn), 256, 0, stream>>>(v1, v2, kern, out);
  }
}